// Round 11
// baseline (184.055 us; speedup 1.0000x reference)
//
#include <hip/hip_runtime.h>
#include <hip/hip_bf16.h>
#include <math.h>

#define TOKENS 16384
#define DIM 4096
#define NEXP 64
#define TOPK 8
#define FILTER_R 0.62f
#define LOAD_LR 0.001f
#define EPS_GAP 1e-4f      // bf16x3 logit err ~4e-6 RMS incl. partial-sum; 25x margin

typedef __attribute__((ext_vector_type(8))) short bf16x8;
typedef __attribute__((ext_vector_type(4))) float f32x4;

#define NSTEP 128                  // total K-steps of 32
#define KB 16                      // K-blocks (gemm grid dim)
#define KSTEPS 8                   // steps per K-block (K=256)
#define PASSES 4                   // token passes per block: 4 x 8 waves x 16 tok = 512
#define BFRAG_U4 (NSTEP * 4 * 64)  // 32768 uint4 = 512KB per array
#define PART_ELEMS ((size_t)KB * TOKENS * NEXP)   // 16.7M floats = 64MB

// ws: partial[64MB] | Bhi[512KB] | Blo[512KB] | hist[64] | flag_cnt | done_cnt | flag_list

__device__ __forceinline__ unsigned bf16_hi_bits(unsigned u) {
    return (u + 0x7fffu + ((u >> 16) & 1u)) & 0xffff0000u;   // RTNE bf16 (as f32 bits)
}

// Coalesced pack (R10-verified mapping): thread tid=((s*4+f)*64+lane) emits the
// 8 consecutive-k elems of one B-fragment slot: n=f*16+(lane&15), k=s*32+(lane>>4)*8+e
__global__ void pack_kernel(const float* __restrict__ W,
                            uint4* __restrict__ Bhi,
                            uint4* __restrict__ Blo,
                            int* __restrict__ hist) {
    int tid = blockIdx.x * blockDim.x + threadIdx.x;     // 0 .. 32767
    if (blockIdx.x == 0 && threadIdx.x < NEXP + 2) hist[threadIdx.x] = 0;
    int s = tid >> 8, f = (tid >> 6) & 3, lane = tid & 63;
    int n = f * 16 + (lane & 15);
    int k0 = s * 32 + ((lane >> 4) << 3);
    const float* wp = W + (size_t)n * DIM + k0;
    float4 wa = *(const float4*)wp;
    float4 wb = *(const float4*)(wp + 4);
    float fe[8] = {wa.x, wa.y, wa.z, wa.w, wb.x, wb.y, wb.z, wb.w};
    unsigned hh[8], ll[8];
#pragma unroll
    for (int e = 0; e < 8; ++e) {
        unsigned u = __float_as_uint(fe[e]);
        unsigned hr = bf16_hi_bits(u);
        hh[e] = hr >> 16;
        float lo = fe[e] - __uint_as_float(hr);
        ll[e] = bf16_hi_bits(__float_as_uint(lo)) >> 16;
    }
    Bhi[tid] = make_uint4(hh[0] | (hh[1] << 16), hh[2] | (hh[3] << 16),
                          hh[4] | (hh[5] << 16), hh[6] | (hh[7] << 16));
    Blo[tid] = make_uint4(ll[0] | (ll[1] << 16), ll[2] | (ll[3] << 16),
                          ll[4] | (ll[5] << 16), ll[6] | (ll[7] << 16));
}

#define MF(A, B, C) C = __builtin_amdgcn_mfma_f32_16x16x32_bf16(A, B, C, 0, 0, 0)

#define SPLIT8(A0, A1, AH, AL) {                                      \
    float fe[8] = {A0.x,A0.y,A0.z,A0.w,A1.x,A1.y,A1.z,A1.w};          \
    short he[8], le[8];                                               \
    _Pragma("unroll")                                                 \
    for (int e_ = 0; e_ < 8; ++e_) {                                  \
        unsigned u_ = __float_as_uint(fe[e_]);                        \
        unsigned hr_ = bf16_hi_bits(u_);                              \
        he[e_] = (short)(hr_ >> 16);                                  \
        float lo_ = fe[e_] - __uint_as_float(hr_);                    \
        le[e_] = (short)(bf16_hi_bits(__float_as_uint(lo_)) >> 16); } \
    AH = (bf16x8){he[0],he[1],he[2],he[3],he[4],he[5],he[6],he[7]};   \
    AL = (bf16x8){le[0],le[1],le[2],le[3],le[4],le[5],le[6],le[7]}; }

// ---- gemm: 512 blocks (32 token-groups x 16 K-blocks) x 512 thr (8 waves) ----
// B-slice (64KB hi+lo) staged to LDS ONCE; K-loop barrier-free; B via ds_read,
// x via 3-deep register prefetch; fp32 partials to ws (disjoint -> deterministic).
__global__ __launch_bounds__(512, 4) void gemm_kernel(
    const float* __restrict__ x,
    const uint4* __restrict__ Bh4,
    const uint4* __restrict__ Bl4,
    float* __restrict__ part) {
    __shared__ uint4 bs[2 * KSTEPS * 4 * 64];   // [0,2048)=hi, [2048,4096)=lo; 64KB

    const int lane = threadIdx.x & 63;
    const int wave = __builtin_amdgcn_readfirstlane(threadIdx.x >> 6);  // 0..7
    const int tg = blockIdx.x >> 4;            // token group 0..31 (512 tokens)
    const int kb = blockIdx.x & 15;            // K-block 0..15 (K=256 slice)

    // stage B slice: linear 2048 uint4 (hi) + 2048 (lo); wave w stages 256 each
    {
        const int gbase = kb * (KSTEPS * 4 * 64);
#pragma unroll
        for (int i = 0; i < 4; ++i) {
            const int o = wave * 256 + i * 64;
            __builtin_amdgcn_global_load_lds(
                (const __attribute__((address_space(1))) void*)(Bh4 + gbase + o + lane),
                (__attribute__((address_space(3))) void*)&bs[o], 16, 0, 0);
            __builtin_amdgcn_global_load_lds(
                (const __attribute__((address_space(1))) void*)(Bl4 + gbase + o + lane),
                (__attribute__((address_space(3))) void*)&bs[2048 + o], 16, 0, 0);
        }
    }
    __syncthreads();    // one-time vmcnt drain + barrier; K-loop has none

    const int row_a = lane & 15;
    const int kg = lane >> 4;
    const float* xb = x + ((size_t)(tg * 512 + row_a)) * DIM + kb * 256 + kg * 8;
    // virtual step v = p*8+s: row offset (v>>3)*128 + wave*16, col (v&7)*32
#define XADDR(V) (xb + ((size_t)(((V) >> 3) * 128 + wave * 16)) * DIM + ((V) & 7) * 32)

    float4 xa[3], xc[3];
    xa[0] = *(const float4*)XADDR(0); xc[0] = *(const float4*)(XADDR(0) + 4);
    xa[1] = *(const float4*)XADDR(1); xc[1] = *(const float4*)(XADDR(1) + 4);

#pragma unroll
    for (int p = 0; p < PASSES; ++p) {
        f32x4 acc0 = {0,0,0,0}, acc1 = {0,0,0,0}, acc2 = {0,0,0,0}, acc3 = {0,0,0,0};
#pragma unroll
        for (int s = 0; s < KSTEPS; ++s) {
            const int v = p * 8 + s;
            const int cur = v % 3, nx = (v + 2) % 3;
            if (v + 2 < 32) {
                xa[nx] = *(const float4*)XADDR(v + 2);
                xc[nx] = *(const float4*)(XADDR(v + 2) + 4);
            }
            bf16x8 ah, al;
            SPLIT8(xa[cur], xc[cur], ah, al);
            const int sb = s * 4;
            {
                uint4 bh = bs[(sb + 0) * 64 + lane], bl = bs[2048 + (sb + 0) * 64 + lane];
                bf16x8 bbh = __builtin_bit_cast(bf16x8, bh);
                bf16x8 bbl = __builtin_bit_cast(bf16x8, bl);
                MF(ah, bbh, acc0); MF(al, bbh, acc0); MF(ah, bbl, acc0);
            }
            {
                uint4 bh = bs[(sb + 1) * 64 + lane], bl = bs[2048 + (sb + 1) * 64 + lane];
                bf16x8 bbh = __builtin_bit_cast(bf16x8, bh);
                bf16x8 bbl = __builtin_bit_cast(bf16x8, bl);
                MF(ah, bbh, acc1); MF(al, bbh, acc1); MF(ah, bbl, acc1);
            }
            {
                uint4 bh = bs[(sb + 2) * 64 + lane], bl = bs[2048 + (sb + 2) * 64 + lane];
                bf16x8 bbh = __builtin_bit_cast(bf16x8, bh);
                bf16x8 bbl = __builtin_bit_cast(bf16x8, bl);
                MF(ah, bbh, acc2); MF(al, bbh, acc2); MF(ah, bbl, acc2);
            }
            {
                uint4 bh = bs[(sb + 3) * 64 + lane], bl = bs[2048 + (sb + 3) * 64 + lane];
                bf16x8 bbh = __builtin_bit_cast(bf16x8, bh);
                bf16x8 bbl = __builtin_bit_cast(bf16x8, bl);
                MF(ah, bbh, acc3); MF(al, bbh, acc3); MF(ah, bbl, acc3);
            }
        }
        // partial write: C layout col=lane&15 (expert in f-group), row=kg*4+r (token)
        float* pp = part + ((size_t)kb * TOKENS + (size_t)(tg * 512 + p * 128 + wave * 16)) * NEXP;
#pragma unroll
        for (int r = 0; r < 4; ++r) {
            const int tr = kg * 4 + r;
            pp[tr * NEXP +  0 + row_a] = acc0[r];
            pp[tr * NEXP + 16 + row_a] = acc1[r];
            pp[tr * NEXP + 32 + row_a] = acc2[r];
            pp[tr * NEXP + 48 + row_a] = acc3[r];
        }
    }
#undef XADDR
}

// ---- topk: 1024 blocks x 256 thr (4 waves x 4 tokens); fixed-order K reduce ----
__global__ __launch_bounds__(256) void topk_kernel(
    const float* __restrict__ part,
    const float* __restrict__ b,
    const float* __restrict__ bi,
    const float* __restrict__ rand_u,
    float* __restrict__ out,
    int* __restrict__ hist_g) {
    __shared__ int lds_hist[NEXP];
    const int lane = threadIdx.x & 63;
    const int wave = __builtin_amdgcn_readfirstlane(threadIdx.x >> 6);
    if (threadIdx.x < NEXP) lds_hist[threadIdx.x] = 0;
    __syncthreads();

    const float b_lane  = b[lane];
    const float bi_lane = bi[lane];
    int* flag_cnt  = hist_g + NEXP;
    int* flag_list = hist_g + NEXP + 2;

    const int tbase = blockIdx.x * 16 + wave * 4;
    for (int t = tbase; t < tbase + 4; ++t) {
        float v = 0.f;
#pragma unroll
        for (int k = 0; k < KB; ++k)                       // fixed order: deterministic
            v += part[(size_t)k * TOKENS * NEXP + (size_t)t * NEXP + lane];
        const float vub = v + b_lane;
        float cur_l = vub + bi_lane;

        float selv = -INFINITY;
        int   selidx = 0;
#pragma unroll
        for (int j = 0; j <= TOPK; ++j) {                  // top-9: check 8/9 gap too
            float bv = cur_l;
            int   bidx = lane;
#pragma unroll
            for (int s = 1; s < 64; s <<= 1) {
                float ov = __shfl_xor(bv, s, 64);
                int   oi = __shfl_xor(bidx, s, 64);
                bool take = (ov > bv) || (ov == bv && oi < bidx);
                if (take) { bv = ov; bidx = oi; }
            }
            if (lane == j) { selv = bv; selidx = bidx; }
            if (lane == bidx) cur_l = -INFINITY;
        }

        float nxtv = __shfl_down(selv, 1, 64);
        bool  bad  = (lane < TOPK) && (selv - nxtv < EPS_GAP);
        if (__any(bad)) {
            if (lane == 0) {
                int p = atomicAdd(flag_cnt, 1);
                if (p < TOKENS) flag_list[p] = t;
            }
        } else {
            float out_logit = __shfl(vub, selidx, 64);
            float sv = (lane < TOPK) ? out_logit : -INFINITY;
            float m = sv;
            m = fmaxf(m, __shfl_xor(m, 1, 64));
            m = fmaxf(m, __shfl_xor(m, 2, 64));
            m = fmaxf(m, __shfl_xor(m, 4, 64));
            float e = (lane < TOPK) ? expf(sv - m) : 0.f;
            float ssum = e;
            ssum += __shfl_xor(ssum, 1, 64);
            ssum += __shfl_xor(ssum, 2, 64);
            ssum += __shfl_xor(ssum, 4, 64);
            if (lane < TOPK) {
                float p = e / ssum;
                float r = rand_u[t * TOPK + lane];
                out[t * TOPK + lane] = (r > FILTER_R) ? p : 0.f;
                out[TOKENS * TOPK + t * TOPK + lane] = (float)selidx;
                atomicAdd(&lds_hist[selidx], 1);
            }
        }
    }

    __syncthreads();
    if (threadIdx.x < NEXP) atomicAdd(&hist_g[threadIdx.x], lds_hist[threadIdx.x]);
}

// exact f64 redo per flagged token (4-wave K-split); last block does bias update
__global__ __launch_bounds__(256) void fallback_kernel(
    const float* __restrict__ x,
    const float* __restrict__ W,
    const float* __restrict__ b,
    const float* __restrict__ bi,
    const float* __restrict__ rand_u,
    float* __restrict__ out,
    int* __restrict__ hist_g) {
    __shared__ double part[4][64];
    __shared__ int last_flag;
    const int lane = threadIdx.x & 63;
    const int wave = threadIdx.x >> 6;
    const int* flag_cnt  = hist_g + NEXP;
    int* done_cnt        = hist_g + NEXP + 1;
    const int* flag_list = hist_g + NEXP + 2;
    int n = *flag_cnt; if (n > TOKENS) n = TOKENS;

    for (int i = blockIdx.x; i < n; i += gridDim.x) {
        const int tt = flag_list[i];
        const float4* xr = (const float4*)(x + (size_t)tt * DIM);
        const float4* wr = (const float4*)(W + (size_t)lane * DIM);
        double d0 = 0.0, d1 = 0.0;
#pragma unroll 8
        for (int k4 = wave * 256; k4 < (wave + 1) * 256; ++k4) {
            float4 xv = xr[k4];
            float4 wv = wr[k4];
            d0 = fma((double)xv.x, (double)wv.x, d0);
            d1 = fma((double)xv.y, (double)wv.y, d1);
            d0 = fma((double)xv.z, (double)wv.z, d0);
            d1 = fma((double)xv.w, (double)wv.w, d1);
        }
        part[wave][lane] = d0 + d1;
        __syncthreads();
        if (wave == 0) {
            const double dvub = ((part[0][lane] + part[1][lane]) +
                                 (part[2][lane] + part[3][lane])) + (double)b[lane];
            double dcur = dvub + (double)bi[lane];
            float out_logit = -INFINITY;
            int   out_idx   = 0;
#pragma unroll
            for (int j = 0; j < TOPK; ++j) {
                double bv = dcur;
                int    bidx = lane;
#pragma unroll
                for (int s = 1; s < 64; s <<= 1) {
                    double ov = __shfl_xor(bv, s, 64);
                    int    oi = __shfl_xor(bidx, s, 64);
                    bool take = (ov > bv) || (ov == bv && oi < bidx);
                    if (take) { bv = ov; bidx = oi; }
                }
                float wub = (float)__shfl(dvub, bidx, 64);
                if (lane == j) { out_logit = wub; out_idx = bidx; }
                if (lane == bidx) dcur = -(double)INFINITY;
            }
            float sv = (lane < TOPK) ? out_logit : -INFINITY;
            float m = sv;
            m = fmaxf(m, __shfl_xor(m, 1, 64));
            m = fmaxf(m, __shfl_xor(m, 2, 64));
            m = fmaxf(m, __shfl_xor(m, 4, 64));
            float e = (lane < TOPK) ? expf(sv - m) : 0.f;
            float ssum = e;
            ssum += __shfl_xor(ssum, 1, 64);
            ssum += __shfl_xor(ssum, 2, 64);
            ssum += __shfl_xor(ssum, 4, 64);
            if (lane < TOPK) {
                float p = e / ssum;
                float r = rand_u[tt * TOPK + lane];
                out[tt * TOPK + lane] = (r > FILTER_R) ? p : 0.f;
                out[TOKENS * TOPK + tt * TOPK + lane] = (float)out_idx;
                atomicAdd(&hist_g[out_idx], 1);
            }
        }
        __syncthreads();
    }

    __threadfence();
    if (threadIdx.x == 0)
        last_flag = (atomicAdd(done_cnt, 1) == (int)gridDim.x - 1);
    __syncthreads();
    if (last_flag && threadIdx.x < NEXP) {
        int c = atomicAdd(&hist_g[threadIdx.x], 0);
        float e_i = (float)TOKENS / (float)NEXP - (float)c;
        float s = (e_i > 0.f) ? 1.f : ((e_i < 0.f) ? -1.f : 0.f);
        out[2 * TOKENS * TOPK + threadIdx.x] = bi[threadIdx.x] + LOAD_LR * s;
    }
}

extern "C" void kernel_launch(void* const* d_in, const int* in_sizes, int n_in,
                              void* d_out, int out_size, void* d_ws, size_t ws_size,
                              hipStream_t stream) {
    const float* x      = (const float*)d_in[0];
    const float* W      = (const float*)d_in[1];
    const float* b      = (const float*)d_in[2];
    const float* bi     = (const float*)d_in[3];
    const float* rand_u = (const float*)d_in[4];

    float* out   = (float*)d_out;
    float* partg = (float*)d_ws;
    uint4* Bhi   = (uint4*)(partg + PART_ELEMS);
    uint4* Blo   = Bhi + BFRAG_U4;
    int*   hist  = (int*)(Blo + BFRAG_U4);

    // 1) pack W -> bf16 hi/lo MFMA B-fragments; zero hist/flag/done
    pack_kernel<<<(NSTEP * 4 * 64) / 256, 256, 0, stream>>>(W, Bhi, Blo, hist);

    // 2) GEMM: B-slice in LDS (staged once), barrier-free K-loop, fp32 partials
    gemm_kernel<<<32 * KB, 512, 0, stream>>>(x, Bhi, Blo, partg);

    // 3) fixed-order reduce + top-k + softmax + hist; near-ties -> flag list
    topk_kernel<<<TOKENS / 16, 256, 0, stream>>>(partg, b, bi, rand_u, out, hist);

    // 4) exact f64 redo for flagged tokens + fused bias update
    fallback_kernel<<<256, 256, 0, stream>>>(x, W, b, bi, rand_u, out, hist);
}

// Round 12
// 174.878 us; speedup vs baseline: 1.0525x; 1.0525x over previous
//
#include <hip/hip_runtime.h>
#include <hip/hip_bf16.h>
#include <math.h>

#define TOKENS 16384
#define DIM 4096
#define NEXP 64
#define TOPK 8
#define FILTER_R 0.62f
#define LOAD_LR 0.001f
#define EPS_GAP 1e-4f      // bf16x3 logit err ~1e-6 RMS; 100x margin

typedef __attribute__((ext_vector_type(8))) short bf16x8;
typedef __attribute__((ext_vector_type(4))) float f32x4;

#define NSTEP 128                  // total K-steps of 32
#define KSPLIT 4                   // waves per block, each owns 32 steps
#define STEPS (NSTEP / KSPLIT)     // 32
#define TPB 16                     // tokens per block (one M-tile)
#define BFRAG_U4 (NSTEP * 4 * 64)  // 32768 uint4 = 512KB per array

// ws: Bhi[512KB] | Blo[512KB] | hist[64] | flag_cnt | done_cnt | flag_list[16384]

__device__ __forceinline__ unsigned bf16_hi_bits(unsigned u) {
    return (u + 0x7fffu + ((u >> 16) & 1u)) & 0xffff0000u;   // RTNE bf16 (as f32 bits)
}

// Coalesced pack (R10-verified mapping): thread tid=((s*4+f)*64+lane) emits the
// 8 consecutive-k elems of one B-fragment slot: n=f*16+(lane&15), k=s*32+(lane>>4)*8+e
__global__ void pack_kernel(const float* __restrict__ W,
                            uint4* __restrict__ Bhi,
                            uint4* __restrict__ Blo,
                            int* __restrict__ hist) {
    int tid = blockIdx.x * blockDim.x + threadIdx.x;     // 0 .. 32767
    if (blockIdx.x == 0 && threadIdx.x < NEXP + 2) hist[threadIdx.x] = 0;
    int s = tid >> 8, f = (tid >> 6) & 3, lane = tid & 63;
    int n = f * 16 + (lane & 15);
    int k0 = s * 32 + ((lane >> 4) << 3);
    const float* wp = W + (size_t)n * DIM + k0;
    float4 wa = *(const float4*)wp;
    float4 wb = *(const float4*)(wp + 4);
    float fe[8] = {wa.x, wa.y, wa.z, wa.w, wb.x, wb.y, wb.z, wb.w};
    unsigned hh[8], ll[8];
#pragma unroll
    for (int e = 0; e < 8; ++e) {
        unsigned u = __float_as_uint(fe[e]);
        unsigned hr = bf16_hi_bits(u);
        hh[e] = hr >> 16;
        float lo = fe[e] - __uint_as_float(hr);
        ll[e] = bf16_hi_bits(__float_as_uint(lo)) >> 16;
    }
    Bhi[tid] = make_uint4(hh[0] | (hh[1] << 16), hh[2] | (hh[3] << 16),
                          hh[4] | (hh[5] << 16), hh[6] | (hh[7] << 16));
    Blo[tid] = make_uint4(ll[0] | (ll[1] << 16), ll[2] | (ll[3] << 16),
                          ll[4] | (ll[5] << 16), ll[6] | (ll[7] << 16));
}

#define MF(A, B, C) C = __builtin_amdgcn_mfma_f32_16x16x32_bf16(A, B, C, 0, 0, 0)

#define SPLIT8(A0, A1, AH, AL) {                                      \
    float fe[8] = {A0.x,A0.y,A0.z,A0.w,A1.x,A1.y,A1.z,A1.w};          \
    short he[8], le[8];                                               \
    _Pragma("unroll")                                                 \
    for (int e_ = 0; e_ < 8; ++e_) {                                  \
        unsigned u_ = __float_as_uint(fe[e_]);                        \
        unsigned hr_ = bf16_hi_bits(u_);                              \
        he[e_] = (short)(hr_ >> 16);                                  \
        float lo_ = fe[e_] - __uint_as_float(hr_);                    \
        le[e_] = (short)(bf16_hi_bits(__float_as_uint(lo_)) >> 16); } \
    AH = (bf16x8){he[0],he[1],he[2],he[3],he[4],he[5],he[6],he[7]};   \
    AL = (bf16x8){le[0],le[1],le[2],le[3],le[4],le[5],le[6],le[7]}; }

#define LOADX(S, SL) {                                        \
    xp0[SL] = *(const float4*)(xrow0 + (size_t)(S) * 32);     \
    xp1[SL] = *(const float4*)(xrow0 + (size_t)(S) * 32 + 4); }

#define LOADB(S) { const int bb_ = (S) * 256 + lane;                 \
    h0 = Bh4[bb_];       h1 = Bh4[bb_ + 64];                         \
    h2 = Bh4[bb_ + 128]; h3 = Bh4[bb_ + 192];                        \
    l0 = Bl4[bb_];       l1 = Bl4[bb_ + 64];                         \
    l2 = Bl4[bb_ + 128]; l3 = Bl4[bb_ + 192]; }

#define COMPUTE1(SL) {                                                   \
    bf16x8 pah, pal, b_;                                                 \
    SPLIT8(xp0[SL], xp1[SL], pah, pal);                                  \
    b_ = __builtin_bit_cast(bf16x8, h0);                                 \
    MF(pah,b_,acc0); MF(pal,b_,acc0);                                    \
    b_ = __builtin_bit_cast(bf16x8, l0);                                 \
    MF(pah,b_,acc0);                                                     \
    b_ = __builtin_bit_cast(bf16x8, h1);                                 \
    MF(pah,b_,acc1); MF(pal,b_,acc1);                                    \
    b_ = __builtin_bit_cast(bf16x8, l1);                                 \
    MF(pah,b_,acc1);                                                     \
    b_ = __builtin_bit_cast(bf16x8, h2);                                 \
    MF(pah,b_,acc2); MF(pal,b_,acc2);                                    \
    b_ = __builtin_bit_cast(bf16x8, l2);                                 \
    MF(pah,b_,acc2);                                                     \
    b_ = __builtin_bit_cast(bf16x8, h3);                                 \
    MF(pah,b_,acc3); MF(pal,b_,acc3);                                    \
    b_ = __builtin_bit_cast(bf16x8, l3);                                 \
    MF(pah,b_,acc3); }

// 1024 blocks x 256 thr (4 waves = 4 K-slices); 16 tokens/block; depth-2 x prefetch
__global__ __launch_bounds__(256, 4) void router_kernel(
    const float* __restrict__ x,
    const float* __restrict__ b,
    const float* __restrict__ bi,
    const float* __restrict__ rand_u,
    const uint4* __restrict__ Bh4,
    const uint4* __restrict__ Bl4,
    float* __restrict__ out,          // probs | indices-as-float | bi_new
    int* __restrict__ hist_g) {       // hist[64] | flag_cnt | done_cnt | flag_list
    __shared__ float part[KSPLIT][TPB][NEXP + 1];   // 16.6KB K-partials (+1 pad)
    __shared__ int lds_hist[NEXP];

    const int lane = threadIdx.x & 63;
    const int wave = __builtin_amdgcn_readfirstlane(threadIdx.x >> 6);  // K-slice
    if (threadIdx.x < NEXP) lds_hist[threadIdx.x] = 0;

    const int t0 = blockIdx.x * TPB;
    const int row_a = lane & 15;           // token row / expert col in C
    const int kg = lane >> 4;              // A k-subgroup / C row-group
    const float* xrow0 = x + (size_t)(t0 + row_a) * DIM + kg * 8;
    const int Sb = wave * STEPS;

    f32x4 acc0 = {0,0,0,0}, acc1 = {0,0,0,0}, acc2 = {0,0,0,0}, acc3 = {0,0,0,0};

    float4 xp0[3], xp1[3];                 // 3 slots, statically indexed (full unroll)
    uint4 h0, h1, h2, h3, l0, l1, l2, l3;

    LOADX(Sb + 0, 0);
    LOADX(Sb + 1, 1);
#pragma unroll
    for (int s = 0; s < STEPS; ++s) {
        if (s + 2 < STEPS) LOADX(Sb + s + 2, (s + 2) % 3);   // depth-2 lookahead
        LOADB(Sb + s);
        COMPUTE1(s % 3);
    }

    // C layout: col = lane&15 (expert within f-group), row = kg*4+r (token)
#pragma unroll
    for (int r = 0; r < 4; ++r) {
        const int tr = kg * 4 + r;
        part[wave][tr][ 0 + row_a] = acc0[r];
        part[wave][tr][16 + row_a] = acc1[r];
        part[wave][tr][32 + row_a] = acc2[r];
        part[wave][tr][48 + row_a] = acc3[r];
    }
    __syncthreads();

    const float b_lane  = b[lane];
    const float bi_lane = bi[lane];
    int* flag_cnt  = hist_g + NEXP;
    int* flag_list = hist_g + NEXP + 2;

    for (int t = wave * 4; t < wave * 4 + 4; ++t) {
        const float vub = ((part[0][t][lane] + part[1][t][lane]) +
                           (part[2][t][lane] + part[3][t][lane])) + b_lane;
        float cur_l = vub + bi_lane;

        float selv  = -INFINITY;
        int   selidx = 0;
#pragma unroll
        for (int j = 0; j <= TOPK; ++j) {       // top-9: gap-check 8/9 boundary too
            float bv = cur_l;
            int   bidx = lane;
#pragma unroll
            for (int s = 1; s < 64; s <<= 1) {
                float ov = __shfl_xor(bv, s, 64);
                int   oi = __shfl_xor(bidx, s, 64);
                bool take = (ov > bv) || (ov == bv && oi < bidx);
                if (take) { bv = ov; bidx = oi; }
            }
            if (lane == j) { selv = bv; selidx = bidx; }
            if (lane == bidx) cur_l = -INFINITY;
        }

        const int tt = t0 + t;
        float nxtv = __shfl_down(selv, 1, 64);
        bool  bad  = (lane < TOPK) && (selv - nxtv < EPS_GAP);
        if (__any(bad)) {
            if (lane == 0) {
                int p = atomicAdd(flag_cnt, 1);
                if (p < TOKENS) flag_list[p] = tt;
            }
        } else {
            float out_logit = __shfl(vub, selidx, 64);
            float sv = (lane < TOPK) ? out_logit : -INFINITY;
            float m = sv;
            m = fmaxf(m, __shfl_xor(m, 1, 64));
            m = fmaxf(m, __shfl_xor(m, 2, 64));
            m = fmaxf(m, __shfl_xor(m, 4, 64));
            float e = (lane < TOPK) ? expf(sv - m) : 0.f;
            float ssum = e;
            ssum += __shfl_xor(ssum, 1, 64);
            ssum += __shfl_xor(ssum, 2, 64);
            ssum += __shfl_xor(ssum, 4, 64);
            if (lane < TOPK) {
                float p = e / ssum;
                float r = rand_u[tt * TOPK + lane];
                out[tt * TOPK + lane] = (r > FILTER_R) ? p : 0.f;
                out[TOKENS * TOPK + tt * TOPK + lane] = (float)selidx;
                atomicAdd(&lds_hist[selidx], 1);
            }
        }
    }

    __syncthreads();
    if (threadIdx.x < NEXP) atomicAdd(&hist_g[threadIdx.x], lds_hist[threadIdx.x]);
}

// exact f64 redo per flagged token (4-wave K-split); last block does bias update
__global__ __launch_bounds__(256) void fallback_kernel(
    const float* __restrict__ x,
    const float* __restrict__ W,
    const float* __restrict__ b,
    const float* __restrict__ bi,
    const float* __restrict__ rand_u,
    float* __restrict__ out,
    int* __restrict__ hist_g) {
    __shared__ double part[4][64];
    __shared__ int last_flag;
    const int lane = threadIdx.x & 63;
    const int wave = threadIdx.x >> 6;
    const int* flag_cnt  = hist_g + NEXP;
    int* done_cnt        = hist_g + NEXP + 1;
    const int* flag_list = hist_g + NEXP + 2;
    int n = *flag_cnt; if (n > TOKENS) n = TOKENS;

    for (int i = blockIdx.x; i < n; i += gridDim.x) {
        const int tt = flag_list[i];
        const float4* xr = (const float4*)(x + (size_t)tt * DIM);
        const float4* wr = (const float4*)(W + (size_t)lane * DIM);
        double d0 = 0.0, d1 = 0.0;
#pragma unroll 8
        for (int k4 = wave * 256; k4 < (wave + 1) * 256; ++k4) {
            float4 xv = xr[k4];
            float4 wv = wr[k4];
            d0 = fma((double)xv.x, (double)wv.x, d0);
            d1 = fma((double)xv.y, (double)wv.y, d1);
            d0 = fma((double)xv.z, (double)wv.z, d0);
            d1 = fma((double)xv.w, (double)wv.w, d1);
        }
        part[wave][lane] = d0 + d1;
        __syncthreads();
        if (wave == 0) {
            const double dvub = ((part[0][lane] + part[1][lane]) +
                                 (part[2][lane] + part[3][lane])) + (double)b[lane];
            double dcur = dvub + (double)bi[lane];
            float out_logit = -INFINITY;
            int   out_idx   = 0;
#pragma unroll
            for (int j = 0; j < TOPK; ++j) {
                double bv = dcur;
                int    bidx = lane;
#pragma unroll
                for (int s = 1; s < 64; s <<= 1) {
                    double ov = __shfl_xor(bv, s, 64);
                    int    oi = __shfl_xor(bidx, s, 64);
                    bool take = (ov > bv) || (ov == bv && oi < bidx);
                    if (take) { bv = ov; bidx = oi; }
                }
                float wub = (float)__shfl(dvub, bidx, 64);
                if (lane == j) { out_logit = wub; out_idx = bidx; }
                if (lane == bidx) dcur = -(double)INFINITY;
            }
            float sv = (lane < TOPK) ? out_logit : -INFINITY;
            float m = sv;
            m = fmaxf(m, __shfl_xor(m, 1, 64));
            m = fmaxf(m, __shfl_xor(m, 2, 64));
            m = fmaxf(m, __shfl_xor(m, 4, 64));
            float e = (lane < TOPK) ? expf(sv - m) : 0.f;
            float ssum = e;
            ssum += __shfl_xor(ssum, 1, 64);
            ssum += __shfl_xor(ssum, 2, 64);
            ssum += __shfl_xor(ssum, 4, 64);
            if (lane < TOPK) {
                float p = e / ssum;
                float r = rand_u[tt * TOPK + lane];
                out[tt * TOPK + lane] = (r > FILTER_R) ? p : 0.f;
                out[TOKENS * TOPK + tt * TOPK + lane] = (float)out_idx;
                atomicAdd(&hist_g[out_idx], 1);
            }
        }
        __syncthreads();
    }

    __threadfence();
    if (threadIdx.x == 0)
        last_flag = (atomicAdd(done_cnt, 1) == (int)gridDim.x - 1);
    __syncthreads();
    if (last_flag && threadIdx.x < NEXP) {
        int c = atomicAdd(&hist_g[threadIdx.x], 0);
        float e_i = (float)TOKENS / (float)NEXP - (float)c;
        float s = (e_i > 0.f) ? 1.f : ((e_i < 0.f) ? -1.f : 0.f);
        out[2 * TOKENS * TOPK + threadIdx.x] = bi[threadIdx.x] + LOAD_LR * s;
    }
}

extern "C" void kernel_launch(void* const* d_in, const int* in_sizes, int n_in,
                              void* d_out, int out_size, void* d_ws, size_t ws_size,
                              hipStream_t stream) {
    const float* x      = (const float*)d_in[0];
    const float* W      = (const float*)d_in[1];
    const float* b      = (const float*)d_in[2];
    const float* bi     = (const float*)d_in[3];
    const float* rand_u = (const float*)d_in[4];

    float* out = (float*)d_out;
    uint4* Bhi = (uint4*)d_ws;
    uint4* Blo = Bhi + BFRAG_U4;
    int*   hist = (int*)(Blo + BFRAG_U4);

    // 1) pack W -> bf16 hi/lo MFMA B-fragments; zero hist/flag/done
    pack_kernel<<<(NSTEP * 4 * 64) / 256, 256, 0, stream>>>(W, Bhi, Blo, hist);

    // 2) bf16x3 MFMA logits (4-way K-split, depth-2 x prefetch, 4 blocks/CU)
    router_kernel<<<TOKENS / TPB, 256, 0, stream>>>(
        x, b, bi, rand_u, Bhi, Blo, out, hist);

    // 3) exact f64 redo for flagged tokens + fused bias update
    fallback_kernel<<<256, 256, 0, stream>>>(x, W, b, bi, rand_u, out, hist);
}